// Round 4
// baseline (513.539 us; speedup 1.0000x reference)
//
#include <hip/hip_runtime.h>
#include <math.h>

// GCN 4-layer, N=100k, E=3.2M. Round 4:
//  - k_bucket partitions by HARDWARE XCD id (s_getreg HW_REG_XCC_ID) so each
//    bucket tail line is owned by one XCD L2 -> evicted full, not per-append.
//    (round 3 evidence: blockIdx&7 partition gave 118MB writes = eviction
//    every ~2.2 appends; blockIdx is NOT round-robin across XCDs.)
// Identities: norm factorizes (dinv pre/post scale); matmul commutes with
// segment-sum, so layers 1/4 aggregate scalars.

#define BLK 256
#define CAP 1024         // per-(bucket,xcd) capacity; mean 512, tolerates ~20% skew

// HW_REG_XCC_ID = id 20, offset 0, size 4  ->  ((4-1)<<11) | (0<<6) | 20
#define XCC_HWREG 6164

// phase 1: append packed (src | localdst<<17) into bucket (dst>>7), partition = XCD id
__global__ void k_bucket(const int* __restrict__ src, const int* __restrict__ dst,
                         int* __restrict__ cur, int* __restrict__ bkt, int E) {
    int e = blockIdx.x * BLK + threadIdx.x;
    int p = (int)(__builtin_amdgcn_s_getreg(XCC_HWREG) & 7u);
    if (e < E) {
        int d = dst[e];
        int s = src[e];
        int b = d >> 7;
        int idx = atomicAdd(&cur[b * 8 + p], 1);
        if (idx < CAP) bkt[(b * 8 + p) * CAP + idx] = s | ((d & 127) << 17);
    }
}

// exclusive scan of per-bucket totals (sum over 8 partitions); single block
__global__ void k_bucket_scan(const int* __restrict__ cur, int* __restrict__ base, int NB) {
    __shared__ int sh[BLK];
    int t = threadIdx.x;
    int carry = 0;
    for (int s0 = 0; s0 < NB; s0 += BLK) {
        int i = s0 + t;
        int v = 0;
        if (i < NB) {
            const int* c = &cur[i * 8];
            v = c[0] + c[1] + c[2] + c[3] + c[4] + c[5] + c[6] + c[7];
        }
        sh[t] = v;
        __syncthreads();
        for (int o = 1; o < BLK; o <<= 1) {
            int a = (t >= o) ? sh[t - o] : 0;
            __syncthreads();
            sh[t] += a;
            __syncthreads();
        }
        if (i < NB) base[i] = sh[t] - v + carry;
        carry += sh[BLK - 1];
        __syncthreads();
    }
}

// phase 2: block per bucket -> LDS hist, LDS scan, contiguous scatter into ss;
// also writes rs, dinv, sa
__global__ void k_build(const int* __restrict__ cur, const int* __restrict__ bkt,
                        const int* __restrict__ base, const float* __restrict__ x,
                        int* __restrict__ rs, int* __restrict__ ss,
                        float* __restrict__ dinv, float* __restrict__ sa,
                        int N, int E) {
    __shared__ int cnt[128], lrs[128], lcur[128], szs[8];
    int b = blockIdx.x, t = threadIdx.x;
    int node_base = b << 7;
    if (t < 128) cnt[t] = 0;
    if (t < 8) szs[t] = min(cur[b * 8 + t], CAP);
    __syncthreads();
    for (int p = 0; p < 8; ++p) {
        int sz = szs[p];
        const int* q = &bkt[(b * 8 + p) * CAP];
        for (int k = t; k < sz; k += BLK) atomicAdd(&cnt[(q[k] >> 17) & 127], 1);
    }
    __syncthreads();
    if (t < 128) lrs[t] = cnt[t];
    __syncthreads();
    for (int o = 1; o < 128; o <<= 1) {
        int a = (t >= o && t < 128) ? lrs[t - o] : 0;
        __syncthreads();
        if (t < 128) lrs[t] += a;
        __syncthreads();
    }
    int gb = base[b];
    if (t < 128) {
        int ex = lrs[t] - cnt[t];          // exclusive local scan
        lcur[t] = gb + ex;                  // global cursor
        int i = node_base + t;
        if (i < N) {
            rs[i] = gb + ex;
            float d = rsqrtf((float)cnt[t] + 1.0f);
            dinv[i] = d;
            sa[i] = x[i] * d;
        }
    }
    if (b == 0 && t == 0) rs[N] = E;
    __syncthreads();
    for (int p = 0; p < 8; ++p) {
        int sz = szs[p];
        const int* q = &bkt[(b * 8 + p) * CAP];
        for (int k = t; k < sz; k += BLK) {
            int v = q[k];
            int ld = (v >> 17) & 127;
            int pos = atomicAdd(&lcur[ld], 1);
            ss[pos] = v & 0x1FFFF;
        }
    }
}

// layer 1: scalar gather-reduce + expand by W_in, fused
__global__ void k_l1agg(const int* __restrict__ rs, const int* __restrict__ ss,
                        const float* __restrict__ sa, const float* __restrict__ dinv,
                        const float* __restrict__ Win, const float* __restrict__ bin,
                        float* __restrict__ F0, int N) {
    int t = blockIdx.x * blockDim.x + threadIdx.x;
    int i = t >> 5, l = t & 31;
    if (i >= N) return;
    int beg = rs[i], end = rs[i + 1];
    float s = 0.f;
    for (int e = beg + l; e < end; e += 32) s += sa[ss[e]];
    #pragma unroll
    for (int m = 16; m; m >>= 1) s += __shfl_xor(s, m, 32);
    float h = dinv[i] * (s + sa[i]);
    float v = h * Win[l] + bin[l];
    F0[t] = v > 0.f ? v : 0.f;
}

// G = (F @ W) * dinv, 8 nodes per 256-thread block
__global__ void k_matvec_scale(const float* __restrict__ Fin, const float* __restrict__ W,
                               const float* __restrict__ dinv, float* __restrict__ Fout, int N) {
    __shared__ float sW[1024];
    __shared__ float sH[256];
    int t = threadIdx.x;
    #pragma unroll
    for (int r = 0; r < 4; ++r) sW[r * 256 + t] = W[r * 256 + t];
    int base = blockIdx.x * 8;
    long long gidx = (long long)base * 32 + t;
    sH[t] = (gidx < (long long)N * 32) ? Fin[gidx] : 0.f;
    __syncthreads();
    int il = t >> 5, j = t & 31;
    int i = base + il;
    if (i < N) {
        float acc = 0.f;
        #pragma unroll
        for (int k = 0; k < 32; ++k) acc += sH[il * 32 + k] * sW[k * 32 + j];
        Fout[(long long)i * 32 + j] = acc * dinv[i];
    }
}

// wide aggregate, float4 lanes: 32-lane group per node; sub = lane>>3 handles
// every 4th edge; each lane loads float4 (4 features). 8 edges in flight.
__global__ void k_agg32v4(const int* __restrict__ rs, const int* __restrict__ ss,
                          const float4* __restrict__ G4, const float* __restrict__ dinv,
                          const float* __restrict__ b, float4* __restrict__ Fout4, int N) {
    int t = blockIdx.x * blockDim.x + threadIdx.x;
    int g = t >> 5;
    if (g >= N) return;
    int lane = t & 31, sub = lane >> 3, fl = lane & 7;
    int beg = rs[g], end = rs[g + 1];
    float4 acc;
    if (sub == 0) acc = G4[(long long)g * 8 + fl];        // self loop
    else { acc.x = 0.f; acc.y = 0.f; acc.z = 0.f; acc.w = 0.f; }
    int e = beg + sub;
    for (; e + 4 < end; e += 8) {
        int s0 = ss[e], s1 = ss[e + 4];
        float4 g0 = G4[(long long)s0 * 8 + fl];
        float4 g1 = G4[(long long)s1 * 8 + fl];
        acc.x += g0.x + g1.x; acc.y += g0.y + g1.y;
        acc.z += g0.z + g1.z; acc.w += g0.w + g1.w;
    }
    for (; e < end; e += 4) {
        int s0 = ss[e];
        float4 g0 = G4[(long long)s0 * 8 + fl];
        acc.x += g0.x; acc.y += g0.y; acc.z += g0.z; acc.w += g0.w;
    }
    #pragma unroll
    for (int m = 8; m <= 16; m <<= 1) {
        acc.x += __shfl_xor(acc.x, m);
        acc.y += __shfl_xor(acc.y, m);
        acc.z += __shfl_xor(acc.z, m);
        acc.w += __shfl_xor(acc.w, m);
    }
    if (sub == 0) {
        float4 bb = ((const float4*)b)[fl];
        float d = dinv[g];
        float4 v;
        v.x = d * acc.x + bb.x; v.y = d * acc.y + bb.y;
        v.z = d * acc.z + bb.z; v.w = d * acc.w + bb.w;
        v.x = v.x > 0.f ? v.x : 0.f; v.y = v.y > 0.f ? v.y : 0.f;
        v.z = v.z > 0.f ? v.z : 0.f; v.w = v.w > 0.f ? v.w : 0.f;
        Fout4[(long long)g * 8 + fl] = v;
    }
}

// sa2 = (F . Wout) * dinv
__global__ void k_dot_scale(const float* __restrict__ F, const float* __restrict__ Wout,
                            const float* __restrict__ dinv, float* __restrict__ sa, int N) {
    int i = blockIdx.x * blockDim.x + threadIdx.x;
    if (i < N) {
        const float4* f4 = (const float4*)(F + (long long)i * 32);
        float acc = 0.f;
        #pragma unroll
        for (int q = 0; q < 8; ++q) {
            float4 v = f4[q];
            acc += v.x * Wout[q * 4 + 0] + v.y * Wout[q * 4 + 1]
                 + v.z * Wout[q * 4 + 2] + v.w * Wout[q * 4 + 3];
        }
        sa[i] = acc * dinv[i];
    }
}

// layer 4: scalar gather-reduce + sigmoid, fused
__global__ void k_final_agg(const int* __restrict__ rs, const int* __restrict__ ss,
                            const float* __restrict__ sa, const float* __restrict__ dinv,
                            const float* __restrict__ bout, float* __restrict__ out, int N) {
    int t = blockIdx.x * blockDim.x + threadIdx.x;
    int i = t >> 5, l = t & 31;
    if (i >= N) return;
    int beg = rs[i], end = rs[i + 1];
    float s = 0.f;
    for (int e = beg + l; e < end; e += 32) s += sa[ss[e]];
    #pragma unroll
    for (int m = 16; m; m >>= 1) s += __shfl_xor(s, m, 32);
    if (l == 0) {
        float z = dinv[i] * (s + sa[i]) + bout[0];
        out[i] = 1.0f / (1.0f + expf(-z));
    }
}

extern "C" void kernel_launch(void* const* d_in, const int* in_sizes, int n_in,
                              void* d_out, int out_size, void* d_ws, size_t ws_size,
                              hipStream_t stream) {
    const float* x    = (const float*)d_in[0];
    const int*   ei   = (const int*)  d_in[1];
    const float* Win  = (const float*)d_in[2];
    const float* bin  = (const float*)d_in[3];
    const float* Wmid = (const float*)d_in[4];
    const float* bmid = (const float*)d_in[5];
    const float* Wout = (const float*)d_in[6];
    const float* bout = (const float*)d_in[7];
    float* out = (float*)d_out;

    int N = in_sizes[0];
    int E = in_sizes[1] / 2;
    const int* src = ei;
    const int* dst = ei + E;

    int NB = (N + 127) >> 7;                       // buckets of 128 nodes

    // workspace layout (bkt aliases F0+F1: build finishes before F0 written)
    int* cur   = (int*)d_ws;                       // NB*8 (pad 8192)
    int* base  = cur + 8192;                       // NB   (pad 1024)
    int* rs    = base + 1024;                      // N+1
    int* ss    = rs + N + 1;                       // E
    float* dinv = (float*)(ss + E);                // N
    float* sa   = dinv + N;                        // N
    float* F0   = sa + N;                          // 32N  (aliases bkt)
    float* F1   = F0 + 32 * (size_t)N;             // 32N
    int* bkt    = (int*)F0;                        // NB*8*CAP ints = 25.6MB = F0+F1

    int gN   = (N + BLK - 1) / BLK;
    int gE   = (E + BLK - 1) / BLK;
    int NT   = N * 32;
    int gN32 = (NT + BLK - 1) / BLK;
    int gMV  = (N + 7) / 8;

    // CSR build: bucket-append (XCD-partitioned) -> scan -> per-bucket sort
    hipMemsetAsync(cur, 0, (size_t)NB * 8 * 4, stream);
    k_bucket<<<gE, BLK, 0, stream>>>(src, dst, cur, bkt, E);
    k_bucket_scan<<<1, BLK, 0, stream>>>(cur, base, NB);
    k_build<<<NB, BLK, 0, stream>>>(cur, bkt, base, x, rs, ss, dinv, sa, N, E);

    // layer 1
    k_l1agg<<<gN32, BLK, 0, stream>>>(rs, ss, sa, dinv, Win, bin, F0, N);

    // layer 2
    k_matvec_scale<<<gMV, BLK, 0, stream>>>(F0, Wmid, dinv, F1, N);
    k_agg32v4<<<gN32, BLK, 0, stream>>>(rs, ss, (const float4*)F1, dinv, bmid, (float4*)F0, N);

    // layer 3
    k_matvec_scale<<<gMV, BLK, 0, stream>>>(F0, Wmid, dinv, F1, N);
    k_agg32v4<<<gN32, BLK, 0, stream>>>(rs, ss, (const float4*)F1, dinv, bmid, (float4*)F0, N);

    // layer 4
    k_dot_scale<<<gN, BLK, 0, stream>>>(F0, Wout, dinv, sa, N);
    k_final_agg<<<gN32, BLK, 0, stream>>>(rs, ss, sa, dinv, bout, out, N);
}

// Round 5
// 430.746 us; speedup vs baseline: 1.1922x; 1.1922x over previous
//
#include <hip/hip_runtime.h>
#include <math.h>

// GCN 4-layer, N=100k, E=3.2M. Round 5:
//  - CSR build via LDS-staged block multisplit. Round-3/4 evidence: scattered
//    4B global stores cost ~37B/edge HBM writeback REGARDLESS of XCD
//    partitioning (no write-allocate; sector write-through), and 3.2M
//    contended return-atomics throttle issue. So: per-block LDS sort, one
//    reservation atomic per (block,bucket), linear coalesced flush.
// Identities: norm factorizes (dinv pre/post scale); matmul commutes with
// segment-sum, so layers 1/4 aggregate scalars.

#define BLK 256
#define NBLK 256          // edge-pass blocks
#define MAXCHUNK 12544    // >= ceil(E/NBLK)=12500

// ---- CSR build ----------------------------------------------------------

// pass A: per-block LDS histogram of coarse buckets (dst>>7), add to totals
__global__ void k_hist(const int* __restrict__ dst, int* __restrict__ tot,
                       int E, int chunk) {
    __shared__ int hist[788];
    int t = threadIdx.x;
    for (int i = t; i < 788; i += BLK) hist[i] = 0;
    __syncthreads();
    int b0 = blockIdx.x * chunk;
    int b1 = min(E, b0 + chunk);
    for (int k = b0 + t; k < b1; k += BLK) atomicAdd(&hist[dst[k] >> 7], 1);
    __syncthreads();
    for (int i = t; i < 782; i += BLK)
        if (hist[i]) atomicAdd(&tot[i], hist[i]);
}

// pass B: exclusive scan of 782 totals -> cursor (mutable) + gbase (stable)
__global__ void k_scan782(const int* __restrict__ tot, int* __restrict__ cursor,
                          int* __restrict__ gbase) {
    __shared__ int tmp[BLK];
    int t = threadIdx.x;
    int vals[4];
    int sum = 0;
    int i0 = t * 4;
    if (t < 196) {
        #pragma unroll
        for (int r = 0; r < 4; ++r) { vals[r] = tot[i0 + r]; sum += vals[r]; }
    }
    tmp[t] = sum;
    __syncthreads();
    for (int o = 1; o < BLK; o <<= 1) {
        int a = (t >= o) ? tmp[t - o] : 0;
        __syncthreads();
        tmp[t] += a;
        __syncthreads();
    }
    int ex = tmp[t] - sum;
    if (t < 196) {
        int run = ex;
        #pragma unroll
        for (int r = 0; r < 4; ++r) {
            cursor[i0 + r] = run;
            gbase[i0 + r] = run;
            run += vals[r];
        }
    }
}

// pass C: per-block LDS multisplit + coalesced flush into bucket-contiguous bkt
__global__ void k_place(const int* __restrict__ src, const int* __restrict__ dst,
                        int* __restrict__ cursor, int* __restrict__ bkt,
                        int E, int chunk) {
    __shared__ int hist[788];          // counts, then wbase after reservation
    __shared__ int lofs[788];          // exclusive local scan (stable)
    __shared__ int lcur[788];          // scatter cursor
    __shared__ int tmp[BLK];
    __shared__ int stage[MAXCHUNK];
    int t = threadIdx.x;
    int b0 = blockIdx.x * chunk;
    int b1 = min(E, b0 + chunk);
    int n = b1 - b0;
    for (int i = t; i < 788; i += BLK) hist[i] = 0;
    __syncthreads();
    for (int k = b0 + t; k < b1; k += BLK) atomicAdd(&hist[dst[k] >> 7], 1);
    __syncthreads();
    // scan 784 entries, 4 per thread
    int vals[4];
    int sum = 0;
    int i0 = t * 4;
    if (t < 196) {
        #pragma unroll
        for (int r = 0; r < 4; ++r) { vals[r] = hist[i0 + r]; sum += vals[r]; }
    }
    tmp[t] = sum;
    __syncthreads();
    for (int o = 1; o < BLK; o <<= 1) {
        int a = (t >= o) ? tmp[t - o] : 0;
        __syncthreads();
        tmp[t] += a;
        __syncthreads();
    }
    int ex = tmp[t] - sum;
    __syncthreads();
    if (t < 196) {
        int run = ex;
        #pragma unroll
        for (int r = 0; r < 4; ++r) {
            lofs[i0 + r] = run;
            lcur[i0 + r] = run;
            run += vals[r];
        }
    }
    __syncthreads();
    // reserve global runs: hist[i] becomes wbase[i]
    for (int i = t; i < 782; i += BLK) {
        int c = hist[i];
        hist[i] = c ? atomicAdd(&cursor[i], c) : 0;
    }
    __syncthreads();
    // LDS scatter: stage[] sorted by bucket
    for (int k = b0 + t; k < b1; k += BLK) {
        int d = dst[k], s = src[k];
        int b = d >> 7;
        int p = atomicAdd(&lcur[b], 1);
        stage[p] = s | ((d & 127) << 17);
    }
    __syncthreads();
    // linear flush: position k -> bucket via binary search in lofs
    for (int k = t; k < n; k += BLK) {
        int lo = 0, hi = 781;
        while (lo < hi) {
            int mid = (lo + hi + 1) >> 1;
            if (lofs[mid] <= k) lo = mid; else hi = mid - 1;
        }
        bkt[hist[lo] + (k - lofs[lo])] = stage[k];
    }
}

// pass D: block per bucket -> per-node LDS hist/scan, scatter into ss;
// also writes rs, dinv, sa
__global__ void k_build(const int* __restrict__ gbase, const int* __restrict__ bkt,
                        const float* __restrict__ x,
                        int* __restrict__ rs, int* __restrict__ ss,
                        float* __restrict__ dinv, float* __restrict__ sa,
                        int N, int E) {
    __shared__ int cnt[128], lrs[128], lcur[128];
    int b = blockIdx.x, t = threadIdx.x;
    int node_base = b << 7;
    int gb = gbase[b];
    int sz = gbase[b + 1] - gb;
    if (t < 128) cnt[t] = 0;
    __syncthreads();
    const int* q = bkt + gb;
    for (int k = t; k < sz; k += BLK) atomicAdd(&cnt[(q[k] >> 17) & 127], 1);
    __syncthreads();
    if (t < 128) lrs[t] = cnt[t];
    __syncthreads();
    for (int o = 1; o < 128; o <<= 1) {
        int a = (t >= o && t < 128) ? lrs[t - o] : 0;
        __syncthreads();
        if (t < 128) lrs[t] += a;
        __syncthreads();
    }
    if (t < 128) {
        int ex = lrs[t] - cnt[t];
        lcur[t] = gb + ex;
        int i = node_base + t;
        if (i < N) {
            rs[i] = gb + ex;
            float d = rsqrtf((float)cnt[t] + 1.0f);
            dinv[i] = d;
            sa[i] = x[i] * d;
        }
    }
    if (b == 0 && t == 0) rs[N] = E;
    __syncthreads();
    for (int k = t; k < sz; k += BLK) {
        int v = q[k];
        int pos = atomicAdd(&lcur[(v >> 17) & 127], 1);
        ss[pos] = v & 0x1FFFF;
    }
}

// ---- layers -------------------------------------------------------------

// layer 1: scalar gather-reduce + expand by W_in, fused
__global__ void k_l1agg(const int* __restrict__ rs, const int* __restrict__ ss,
                        const float* __restrict__ sa, const float* __restrict__ dinv,
                        const float* __restrict__ Win, const float* __restrict__ bin,
                        float* __restrict__ F0, int N) {
    int t = blockIdx.x * blockDim.x + threadIdx.x;
    int i = t >> 5, l = t & 31;
    if (i >= N) return;
    int beg = rs[i], end = rs[i + 1];
    float s = 0.f;
    for (int e = beg + l; e < end; e += 32) s += sa[ss[e]];
    #pragma unroll
    for (int m = 16; m; m >>= 1) s += __shfl_xor(s, m, 32);
    float h = dinv[i] * (s + sa[i]);
    float v = h * Win[l] + bin[l];
    F0[t] = v > 0.f ? v : 0.f;
}

// G = (F @ W) * dinv, 8 nodes per 256-thread block
__global__ void k_matvec_scale(const float* __restrict__ Fin, const float* __restrict__ W,
                               const float* __restrict__ dinv, float* __restrict__ Fout, int N) {
    __shared__ float sW[1024];
    __shared__ float sH[256];
    int t = threadIdx.x;
    #pragma unroll
    for (int r = 0; r < 4; ++r) sW[r * 256 + t] = W[r * 256 + t];
    int base = blockIdx.x * 8;
    long long gidx = (long long)base * 32 + t;
    sH[t] = (gidx < (long long)N * 32) ? Fin[gidx] : 0.f;
    __syncthreads();
    int il = t >> 5, j = t & 31;
    int i = base + il;
    if (i < N) {
        float acc = 0.f;
        #pragma unroll
        for (int k = 0; k < 32; ++k) acc += sH[il * 32 + k] * sW[k * 32 + j];
        Fout[(long long)i * 32 + j] = acc * dinv[i];
    }
}

// wide aggregate, float4 lanes: 32-lane group per node; sub = lane>>3 handles
// every 4th edge; each lane loads float4 (4 features). 8 edges in flight.
__global__ void k_agg32v4(const int* __restrict__ rs, const int* __restrict__ ss,
                          const float4* __restrict__ G4, const float* __restrict__ dinv,
                          const float* __restrict__ b, float4* __restrict__ Fout4, int N) {
    int t = blockIdx.x * blockDim.x + threadIdx.x;
    int g = t >> 5;
    if (g >= N) return;
    int lane = t & 31, sub = lane >> 3, fl = lane & 7;
    int beg = rs[g], end = rs[g + 1];
    float4 acc;
    if (sub == 0) acc = G4[(long long)g * 8 + fl];        // self loop
    else { acc.x = 0.f; acc.y = 0.f; acc.z = 0.f; acc.w = 0.f; }
    int e = beg + sub;
    for (; e + 4 < end; e += 8) {
        int s0 = ss[e], s1 = ss[e + 4];
        float4 g0 = G4[(long long)s0 * 8 + fl];
        float4 g1 = G4[(long long)s1 * 8 + fl];
        acc.x += g0.x + g1.x; acc.y += g0.y + g1.y;
        acc.z += g0.z + g1.z; acc.w += g0.w + g1.w;
    }
    for (; e < end; e += 4) {
        int s0 = ss[e];
        float4 g0 = G4[(long long)s0 * 8 + fl];
        acc.x += g0.x; acc.y += g0.y; acc.z += g0.z; acc.w += g0.w;
    }
    #pragma unroll
    for (int m = 8; m <= 16; m <<= 1) {
        acc.x += __shfl_xor(acc.x, m);
        acc.y += __shfl_xor(acc.y, m);
        acc.z += __shfl_xor(acc.z, m);
        acc.w += __shfl_xor(acc.w, m);
    }
    if (sub == 0) {
        float4 bb = ((const float4*)b)[fl];
        float d = dinv[g];
        float4 v;
        v.x = d * acc.x + bb.x; v.y = d * acc.y + bb.y;
        v.z = d * acc.z + bb.z; v.w = d * acc.w + bb.w;
        v.x = v.x > 0.f ? v.x : 0.f; v.y = v.y > 0.f ? v.y : 0.f;
        v.z = v.z > 0.f ? v.z : 0.f; v.w = v.w > 0.f ? v.w : 0.f;
        Fout4[(long long)g * 8 + fl] = v;
    }
}

// sa2 = (F . Wout) * dinv
__global__ void k_dot_scale(const float* __restrict__ F, const float* __restrict__ Wout,
                            const float* __restrict__ dinv, float* __restrict__ sa, int N) {
    int i = blockIdx.x * blockDim.x + threadIdx.x;
    if (i < N) {
        const float4* f4 = (const float4*)(F + (long long)i * 32);
        float acc = 0.f;
        #pragma unroll
        for (int q = 0; q < 8; ++q) {
            float4 v = f4[q];
            acc += v.x * Wout[q * 4 + 0] + v.y * Wout[q * 4 + 1]
                 + v.z * Wout[q * 4 + 2] + v.w * Wout[q * 4 + 3];
        }
        sa[i] = acc * dinv[i];
    }
}

// layer 4: scalar gather-reduce + sigmoid, fused
__global__ void k_final_agg(const int* __restrict__ rs, const int* __restrict__ ss,
                            const float* __restrict__ sa, const float* __restrict__ dinv,
                            const float* __restrict__ bout, float* __restrict__ out, int N) {
    int t = blockIdx.x * blockDim.x + threadIdx.x;
    int i = t >> 5, l = t & 31;
    if (i >= N) return;
    int beg = rs[i], end = rs[i + 1];
    float s = 0.f;
    for (int e = beg + l; e < end; e += 32) s += sa[ss[e]];
    #pragma unroll
    for (int m = 16; m; m >>= 1) s += __shfl_xor(s, m, 32);
    if (l == 0) {
        float z = dinv[i] * (s + sa[i]) + bout[0];
        out[i] = 1.0f / (1.0f + expf(-z));
    }
}

extern "C" void kernel_launch(void* const* d_in, const int* in_sizes, int n_in,
                              void* d_out, int out_size, void* d_ws, size_t ws_size,
                              hipStream_t stream) {
    const float* x    = (const float*)d_in[0];
    const int*   ei   = (const int*)  d_in[1];
    const float* Win  = (const float*)d_in[2];
    const float* bin  = (const float*)d_in[3];
    const float* Wmid = (const float*)d_in[4];
    const float* bmid = (const float*)d_in[5];
    const float* Wout = (const float*)d_in[6];
    const float* bout = (const float*)d_in[7];
    float* out = (float*)d_out;

    int N = in_sizes[0];
    int E = in_sizes[1] / 2;
    const int* src = ei;
    const int* dst = ei + E;

    int NB = (N + 127) >> 7;                       // 782 buckets of 128 nodes
    int chunk = (E + NBLK - 1) / NBLK;             // 12500

    // workspace layout (bkt aliases F0: k_build finishes before F0 written)
    int* tot    = (int*)d_ws;                      // 1024
    int* cursor = tot + 1024;                      // 1024
    int* gbase  = cursor + 1024;                   // 1024 (783 used)
    int* rs     = gbase + 1024;                    // N+1
    int* ss     = rs + N + 1;                      // E
    float* dinv = (float*)(ss + E);                // N
    float* sa   = dinv + N;                        // N
    float* F0   = sa + N;                          // 32N  (aliases bkt, same size)
    float* F1   = F0 + 32 * (size_t)N;             // 32N
    int* bkt    = (int*)F0;                        // E ints

    int gN   = (N + BLK - 1) / BLK;
    int NT   = N * 32;
    int gN32 = (NT + BLK - 1) / BLK;
    int gMV  = (N + 7) / 8;

    // CSR build: hist -> scan -> LDS multisplit place -> per-bucket node sort
    hipMemsetAsync(tot, 0, 1024 * 4, stream);
    k_hist<<<NBLK, BLK, 0, stream>>>(dst, tot, E, chunk);
    k_scan782<<<1, BLK, 0, stream>>>(tot, cursor, gbase);
    k_place<<<NBLK, BLK, 0, stream>>>(src, dst, cursor, bkt, E, chunk);
    k_build<<<NB, BLK, 0, stream>>>(gbase, bkt, x, rs, ss, dinv, sa, N, E);

    // layer 1
    k_l1agg<<<gN32, BLK, 0, stream>>>(rs, ss, sa, dinv, Win, bin, F0, N);

    // layer 2
    k_matvec_scale<<<gMV, BLK, 0, stream>>>(F0, Wmid, dinv, F1, N);
    k_agg32v4<<<gN32, BLK, 0, stream>>>(rs, ss, (const float4*)F1, dinv, bmid, (float4*)F0, N);

    // layer 3
    k_matvec_scale<<<gMV, BLK, 0, stream>>>(F0, Wmid, dinv, F1, N);
    k_agg32v4<<<gN32, BLK, 0, stream>>>(rs, ss, (const float4*)F1, dinv, bmid, (float4*)F0, N);

    // layer 4
    k_dot_scale<<<gN, BLK, 0, stream>>>(F0, Wout, dinv, sa, N);
    k_final_agg<<<gN32, BLK, 0, stream>>>(rs, ss, sa, dinv, bout, out, N);
}

// Round 6
// 343.639 us; speedup vs baseline: 1.4944x; 1.2535x over previous
//
#include <hip/hip_runtime.h>
#include <math.h>

// GCN 4-layer, N=100k, E=3.2M. Round 6:
//  - Message array G stored fp16 (fp32 accumulate): gathered row 128B -> 64B
//    (one line), working set 12.8 -> 6.4MB (~fits per-XCD L2).
//  - k_build's ss scatter staged in LDS, flushed linearly (round-5 lesson:
//    scattered sub-line global stores are ~37B/edge write-through).
// Identities: norm factorizes (dinv pre/post scale); matmul commutes with
// segment-sum, so layers 1/4 aggregate scalars.

#define BLK 256
#define NBLK 256          // edge-pass blocks
#define MAXCHUNK 12544    // >= ceil(E/NBLK)=12500
#define BCAP 6400         // k_build LDS stage cap (bucket mean 4096, +36 sigma)

typedef _Float16 half8 __attribute__((ext_vector_type(8)));

// ---- CSR build ----------------------------------------------------------

// pass A: per-block LDS histogram of coarse buckets (dst>>7), add to totals
__global__ void k_hist(const int* __restrict__ dst, int* __restrict__ tot,
                       int E, int chunk) {
    __shared__ int hist[788];
    int t = threadIdx.x;
    for (int i = t; i < 788; i += BLK) hist[i] = 0;
    __syncthreads();
    int b0 = blockIdx.x * chunk;
    int b1 = min(E, b0 + chunk);
    for (int k = b0 + t; k < b1; k += BLK) atomicAdd(&hist[dst[k] >> 7], 1);
    __syncthreads();
    for (int i = t; i < 782; i += BLK)
        if (hist[i]) atomicAdd(&tot[i], hist[i]);
}

// pass B: exclusive scan of 782 totals -> cursor (mutable) + gbase (stable)
__global__ void k_scan782(const int* __restrict__ tot, int* __restrict__ cursor,
                          int* __restrict__ gbase) {
    __shared__ int tmp[BLK];
    int t = threadIdx.x;
    int vals[4];
    int sum = 0;
    int i0 = t * 4;
    if (t < 196) {
        #pragma unroll
        for (int r = 0; r < 4; ++r) { vals[r] = tot[i0 + r]; sum += vals[r]; }
    }
    tmp[t] = sum;
    __syncthreads();
    for (int o = 1; o < BLK; o <<= 1) {
        int a = (t >= o) ? tmp[t - o] : 0;
        __syncthreads();
        tmp[t] += a;
        __syncthreads();
    }
    int ex = tmp[t] - sum;
    if (t < 196) {
        int run = ex;
        #pragma unroll
        for (int r = 0; r < 4; ++r) {
            cursor[i0 + r] = run;
            gbase[i0 + r] = run;
            run += vals[r];
        }
    }
}

// pass C: per-block LDS multisplit + coalesced flush into bucket-contiguous bkt
__global__ void k_place(const int* __restrict__ src, const int* __restrict__ dst,
                        int* __restrict__ cursor, int* __restrict__ bkt,
                        int E, int chunk) {
    __shared__ int hist[788];          // counts, then wbase after reservation
    __shared__ int lofs[788];          // exclusive local scan (stable)
    __shared__ int lcur[788];          // scatter cursor
    __shared__ int tmp[BLK];
    __shared__ int stage[MAXCHUNK];
    int t = threadIdx.x;
    int b0 = blockIdx.x * chunk;
    int b1 = min(E, b0 + chunk);
    int n = b1 - b0;
    for (int i = t; i < 788; i += BLK) hist[i] = 0;
    __syncthreads();
    for (int k = b0 + t; k < b1; k += BLK) atomicAdd(&hist[dst[k] >> 7], 1);
    __syncthreads();
    int vals[4];
    int sum = 0;
    int i0 = t * 4;
    if (t < 196) {
        #pragma unroll
        for (int r = 0; r < 4; ++r) { vals[r] = hist[i0 + r]; sum += vals[r]; }
    }
    tmp[t] = sum;
    __syncthreads();
    for (int o = 1; o < BLK; o <<= 1) {
        int a = (t >= o) ? tmp[t - o] : 0;
        __syncthreads();
        tmp[t] += a;
        __syncthreads();
    }
    int ex = tmp[t] - sum;
    __syncthreads();
    if (t < 196) {
        int run = ex;
        #pragma unroll
        for (int r = 0; r < 4; ++r) {
            lofs[i0 + r] = run;
            lcur[i0 + r] = run;
            run += vals[r];
        }
    }
    __syncthreads();
    for (int i = t; i < 782; i += BLK) {
        int c = hist[i];
        hist[i] = c ? atomicAdd(&cursor[i], c) : 0;
    }
    __syncthreads();
    for (int k = b0 + t; k < b1; k += BLK) {
        int d = dst[k], s = src[k];
        int b = d >> 7;
        int p = atomicAdd(&lcur[b], 1);
        stage[p] = s | ((d & 127) << 17);
    }
    __syncthreads();
    for (int k = t; k < n; k += BLK) {
        int lo = 0, hi = 781;
        while (lo < hi) {
            int mid = (lo + hi + 1) >> 1;
            if (lofs[mid] <= k) lo = mid; else hi = mid - 1;
        }
        bkt[hist[lo] + (k - lofs[lo])] = stage[k];
    }
}

// pass D: block per bucket -> per-node LDS hist/scan, LDS-staged scatter, flush;
// also writes rs, dinv, sa
__global__ void k_build(const int* __restrict__ gbase, const int* __restrict__ bkt,
                        const float* __restrict__ x,
                        int* __restrict__ rs, int* __restrict__ ss,
                        float* __restrict__ dinv, float* __restrict__ sa,
                        int N, int E) {
    __shared__ int cnt[128], lrs[128], lcur[128];
    __shared__ int stg[BCAP];
    int b = blockIdx.x, t = threadIdx.x;
    int node_base = b << 7;
    int gb = gbase[b];
    int sz = gbase[b + 1] - gb;
    bool staged = (sz <= BCAP);
    if (t < 128) cnt[t] = 0;
    __syncthreads();
    const int* q = bkt + gb;
    for (int k = t; k < sz; k += BLK) atomicAdd(&cnt[(q[k] >> 17) & 127], 1);
    __syncthreads();
    if (t < 128) lrs[t] = cnt[t];
    __syncthreads();
    for (int o = 1; o < 128; o <<= 1) {
        int a = (t >= o && t < 128) ? lrs[t - o] : 0;
        __syncthreads();
        if (t < 128) lrs[t] += a;
        __syncthreads();
    }
    if (t < 128) {
        int ex = lrs[t] - cnt[t];
        lcur[t] = staged ? ex : gb + ex;
        int i = node_base + t;
        if (i < N) {
            rs[i] = gb + ex;
            float d = rsqrtf((float)cnt[t] + 1.0f);
            dinv[i] = d;
            sa[i] = x[i] * d;
        }
    }
    if (b == 0 && t == 0) rs[N] = E;
    __syncthreads();
    if (staged) {
        for (int k = t; k < sz; k += BLK) {
            int v = q[k];
            int pos = atomicAdd(&lcur[(v >> 17) & 127], 1);
            stg[pos] = v & 0x1FFFF;
        }
        __syncthreads();
        for (int k = t; k < sz; k += BLK) ss[gb + k] = stg[k];
    } else {
        for (int k = t; k < sz; k += BLK) {
            int v = q[k];
            int pos = atomicAdd(&lcur[(v >> 17) & 127], 1);
            ss[pos] = v & 0x1FFFF;
        }
    }
}

// ---- layers -------------------------------------------------------------

// layer 1: scalar gather-reduce + expand by W_in, fused
__global__ void k_l1agg(const int* __restrict__ rs, const int* __restrict__ ss,
                        const float* __restrict__ sa, const float* __restrict__ dinv,
                        const float* __restrict__ Win, const float* __restrict__ bin,
                        float* __restrict__ F0, int N) {
    int t = blockIdx.x * blockDim.x + threadIdx.x;
    int i = t >> 5, l = t & 31;
    if (i >= N) return;
    int beg = rs[i], end = rs[i + 1];
    float s = 0.f;
    for (int e = beg + l; e < end; e += 32) s += sa[ss[e]];
    #pragma unroll
    for (int m = 16; m; m >>= 1) s += __shfl_xor(s, m, 32);
    float h = dinv[i] * (s + sa[i]);
    float v = h * Win[l] + bin[l];
    F0[t] = v > 0.f ? v : 0.f;
}

// G(fp16) = (F @ W) * dinv, 8 nodes per 256-thread block
__global__ void k_matvec_scale(const float* __restrict__ Fin, const float* __restrict__ W,
                               const float* __restrict__ dinv, _Float16* __restrict__ Gh, int N) {
    __shared__ float sW[1024];
    __shared__ float sH[256];
    int t = threadIdx.x;
    #pragma unroll
    for (int r = 0; r < 4; ++r) sW[r * 256 + t] = W[r * 256 + t];
    int base = blockIdx.x * 8;
    long long gidx = (long long)base * 32 + t;
    sH[t] = (gidx < (long long)N * 32) ? Fin[gidx] : 0.f;
    __syncthreads();
    int il = t >> 5, j = t & 31;
    int i = base + il;
    if (i < N) {
        float acc = 0.f;
        #pragma unroll
        for (int k = 0; k < 32; ++k) acc += sH[il * 32 + k] * sW[k * 32 + j];
        Gh[(long long)i * 32 + j] = (_Float16)(acc * dinv[i]);
    }
}

// wide aggregate over fp16 rows: 32-lane group per node; sub=lane>>2 (8 edges
// in flight), fl=lane&3; each lane loads half8 (16B = 8 features). fp32 acc.
__global__ void k_agg32h(const int* __restrict__ rs, const int* __restrict__ ss,
                         const half8* __restrict__ G8, const float* __restrict__ dinv,
                         const float* __restrict__ b, float* __restrict__ Fout, int N) {
    int t = blockIdx.x * blockDim.x + threadIdx.x;
    int g = t >> 5;
    if (g >= N) return;
    int lane = t & 31, sub = lane >> 2, fl = lane & 3;
    int beg = rs[g], end = rs[g + 1];
    float acc[8];
    #pragma unroll
    for (int j = 0; j < 8; ++j) acc[j] = 0.f;
    if (sub == 0) {                         // self loop
        half8 v = G8[(long long)g * 4 + fl];
        #pragma unroll
        for (int j = 0; j < 8; ++j) acc[j] = (float)v[j];
    }
    int e = beg + sub;
    for (; e + 8 < end; e += 16) {
        int s0 = ss[e], s1 = ss[e + 8];
        half8 v0 = G8[(long long)s0 * 4 + fl];
        half8 v1 = G8[(long long)s1 * 4 + fl];
        #pragma unroll
        for (int j = 0; j < 8; ++j) acc[j] += (float)v0[j] + (float)v1[j];
    }
    for (; e < end; e += 8) {
        half8 v0 = G8[(long long)ss[e] * 4 + fl];
        #pragma unroll
        for (int j = 0; j < 8; ++j) acc[j] += (float)v0[j];
    }
    #pragma unroll
    for (int j = 0; j < 8; ++j) {
        acc[j] += __shfl_xor(acc[j], 4);
        acc[j] += __shfl_xor(acc[j], 8);
        acc[j] += __shfl_xor(acc[j], 16);
    }
    if (sub == 0) {
        float d = dinv[g];
        float o[8];
        #pragma unroll
        for (int j = 0; j < 8; ++j) {
            float v = d * acc[j] + b[fl * 8 + j];
            o[j] = v > 0.f ? v : 0.f;
        }
        float4* F4 = (float4*)(Fout + (long long)g * 32 + fl * 8);
        F4[0] = make_float4(o[0], o[1], o[2], o[3]);
        F4[1] = make_float4(o[4], o[5], o[6], o[7]);
    }
}

// sa2 = (F . Wout) * dinv
__global__ void k_dot_scale(const float* __restrict__ F, const float* __restrict__ Wout,
                            const float* __restrict__ dinv, float* __restrict__ sa, int N) {
    int i = blockIdx.x * blockDim.x + threadIdx.x;
    if (i < N) {
        const float4* f4 = (const float4*)(F + (long long)i * 32);
        float acc = 0.f;
        #pragma unroll
        for (int q = 0; q < 8; ++q) {
            float4 v = f4[q];
            acc += v.x * Wout[q * 4 + 0] + v.y * Wout[q * 4 + 1]
                 + v.z * Wout[q * 4 + 2] + v.w * Wout[q * 4 + 3];
        }
        sa[i] = acc * dinv[i];
    }
}

// layer 4: scalar gather-reduce + sigmoid, fused
__global__ void k_final_agg(const int* __restrict__ rs, const int* __restrict__ ss,
                            const float* __restrict__ sa, const float* __restrict__ dinv,
                            const float* __restrict__ bout, float* __restrict__ out, int N) {
    int t = blockIdx.x * blockDim.x + threadIdx.x;
    int i = t >> 5, l = t & 31;
    if (i >= N) return;
    int beg = rs[i], end = rs[i + 1];
    float s = 0.f;
    for (int e = beg + l; e < end; e += 32) s += sa[ss[e]];
    #pragma unroll
    for (int m = 16; m; m >>= 1) s += __shfl_xor(s, m, 32);
    if (l == 0) {
        float z = dinv[i] * (s + sa[i]) + bout[0];
        out[i] = 1.0f / (1.0f + expf(-z));
    }
}

extern "C" void kernel_launch(void* const* d_in, const int* in_sizes, int n_in,
                              void* d_out, int out_size, void* d_ws, size_t ws_size,
                              hipStream_t stream) {
    const float* x    = (const float*)d_in[0];
    const int*   ei   = (const int*)  d_in[1];
    const float* Win  = (const float*)d_in[2];
    const float* bin  = (const float*)d_in[3];
    const float* Wmid = (const float*)d_in[4];
    const float* bmid = (const float*)d_in[5];
    const float* Wout = (const float*)d_in[6];
    const float* bout = (const float*)d_in[7];
    float* out = (float*)d_out;

    int N = in_sizes[0];
    int E = in_sizes[1] / 2;
    const int* src = ei;
    const int* dst = ei + E;

    int NB = (N + 127) >> 7;                       // 782 buckets of 128 nodes
    int chunk = (E + NBLK - 1) / NBLK;             // 12500

    // workspace layout (bkt aliases F0: k_build finishes before F0 written).
    // rs padded to N+4 so F0/Gh are 16B-aligned.
    int* tot    = (int*)d_ws;                      // 1024
    int* cursor = tot + 1024;                      // 1024
    int* gbase  = cursor + 1024;                   // 1024 (783 used)
    int* rs     = gbase + 1024;                    // N+4
    int* ss     = rs + N + 4;                      // E
    float* dinv = (float*)(ss + E);                // N
    float* sa   = dinv + N;                        // N
    float* F0   = sa + N;                          // 32N fp32 (aliases bkt)
    _Float16* Gh = (_Float16*)(F0 + 32 * (size_t)N); // 32N fp16
    int* bkt    = (int*)F0;                        // E ints

    int gN   = (N + BLK - 1) / BLK;
    int NT   = N * 32;
    int gN32 = (NT + BLK - 1) / BLK;
    int gMV  = (N + 7) / 8;

    // CSR build: hist -> scan -> LDS multisplit place -> per-bucket node sort
    hipMemsetAsync(tot, 0, 1024 * 4, stream);
    k_hist<<<NBLK, BLK, 0, stream>>>(dst, tot, E, chunk);
    k_scan782<<<1, BLK, 0, stream>>>(tot, cursor, gbase);
    k_place<<<NBLK, BLK, 0, stream>>>(src, dst, cursor, bkt, E, chunk);
    k_build<<<NB, BLK, 0, stream>>>(gbase, bkt, x, rs, ss, dinv, sa, N, E);

    // layer 1
    k_l1agg<<<gN32, BLK, 0, stream>>>(rs, ss, sa, dinv, Win, bin, F0, N);

    // layer 2
    k_matvec_scale<<<gMV, BLK, 0, stream>>>(F0, Wmid, dinv, Gh, N);
    k_agg32h<<<gN32, BLK, 0, stream>>>(rs, ss, (const half8*)Gh, dinv, bmid, F0, N);

    // layer 3
    k_matvec_scale<<<gMV, BLK, 0, stream>>>(F0, Wmid, dinv, Gh, N);
    k_agg32h<<<gN32, BLK, 0, stream>>>(rs, ss, (const half8*)Gh, dinv, bmid, F0, N);

    // layer 4
    k_dot_scale<<<gN, BLK, 0, stream>>>(F0, Wout, dinv, sa, N);
    k_final_agg<<<gN32, BLK, 0, stream>>>(rs, ss, sa, dinv, bout, out, N);
}

// Round 7
// 296.555 us; speedup vs baseline: 1.7317x; 1.1588x over previous
//
#include <hip/hip_runtime.h>
#include <math.h>

// GCN 4-layer, N=100k, E=3.2M. Round 7:
//  - k_place: 1024 threads (was 256) at same 256 blocks / 12500-edge chunk:
//    round-6 counters showed 10% occupancy (1 block/CU, 4 waves) on a
//    latency-bound kernel. Keeps run length ~16 -> coalesced flush.
//  - Fusions: l1agg emits Gh directly (shuffle-matvec epilogue, kills
//    matvec#1); agg3 emits the W_out dot directly (kills dot_scale + 12.8MB
//    F-write); agg2 writes F in fp16 (halves matvec#2 traffic).
// Identities: norm factorizes (dinv pre/post scale); matmul commutes with
// segment-sum, so layers 1/4 aggregate scalars.

#define BLK 256
#define PBLK 1024         // k_place threads
#define NBLK 256          // edge-pass blocks
#define MAXCHUNK 12544    // >= ceil(E/NBLK)=12500
#define BCAP 6400         // k_build LDS stage cap (bucket mean 4096)

typedef _Float16 half8 __attribute__((ext_vector_type(8)));

// ---- CSR build ----------------------------------------------------------

__global__ void k_hist(const int* __restrict__ dst, int* __restrict__ tot,
                       int E, int chunk) {
    __shared__ int hist[788];
    int t = threadIdx.x;
    for (int i = t; i < 788; i += BLK) hist[i] = 0;
    __syncthreads();
    int b0 = blockIdx.x * chunk;
    int b1 = min(E, b0 + chunk);
    for (int k = b0 + t; k < b1; k += BLK) atomicAdd(&hist[dst[k] >> 7], 1);
    __syncthreads();
    for (int i = t; i < 782; i += BLK)
        if (hist[i]) atomicAdd(&tot[i], hist[i]);
}

__global__ void k_scan782(const int* __restrict__ tot, int* __restrict__ cursor,
                          int* __restrict__ gbase) {
    __shared__ int tmp[BLK];
    int t = threadIdx.x;
    int vals[4];
    int sum = 0;
    int i0 = t * 4;
    if (t < 196) {
        #pragma unroll
        for (int r = 0; r < 4; ++r) { vals[r] = tot[i0 + r]; sum += vals[r]; }
    }
    tmp[t] = sum;
    __syncthreads();
    for (int o = 1; o < BLK; o <<= 1) {
        int a = (t >= o) ? tmp[t - o] : 0;
        __syncthreads();
        tmp[t] += a;
        __syncthreads();
    }
    int ex = tmp[t] - sum;
    if (t < 196) {
        int run = ex;
        #pragma unroll
        for (int r = 0; r < 4; ++r) {
            cursor[i0 + r] = run;
            gbase[i0 + r] = run;
            run += vals[r];
        }
    }
}

// per-block LDS multisplit + coalesced flush; 1024 threads for latency hiding
__global__ void __launch_bounds__(PBLK) k_place(
        const int* __restrict__ src, const int* __restrict__ dst,
        int* __restrict__ cursor, int* __restrict__ bkt, int E, int chunk) {
    __shared__ int hist[788];          // counts, then wbase after reservation
    __shared__ int lofs[788];          // exclusive local scan (stable)
    __shared__ int lcur[788];          // scatter cursor
    __shared__ int tmp[PBLK];
    __shared__ int stage[MAXCHUNK];
    int t = threadIdx.x;
    int b0 = blockIdx.x * chunk;
    int b1 = min(E, b0 + chunk);
    int n = b1 - b0;
    if (t < 788) hist[t] = 0;
    __syncthreads();
    for (int k = b0 + t; k < b1; k += PBLK) atomicAdd(&hist[dst[k] >> 7], 1);
    __syncthreads();
    int v = (t < 788) ? hist[t] : 0;
    tmp[t] = v;
    __syncthreads();
    for (int o = 1; o < PBLK; o <<= 1) {
        int a = (t >= o) ? tmp[t - o] : 0;
        __syncthreads();
        tmp[t] += a;
        __syncthreads();
    }
    int ex = tmp[t] - v;
    if (t < 788) { lofs[t] = ex; lcur[t] = ex; }
    __syncthreads();
    if (t < 782) {
        int c = hist[t];
        hist[t] = c ? atomicAdd(&cursor[t], c) : 0;
    }
    __syncthreads();
    for (int k = b0 + t; k < b1; k += PBLK) {
        int d = dst[k], s = src[k];
        int b = d >> 7;
        int p = atomicAdd(&lcur[b], 1);
        stage[p] = s | ((d & 127) << 17);
    }
    __syncthreads();
    for (int k = t; k < n; k += PBLK) {
        int lo = 0, hi = 781;
        while (lo < hi) {
            int mid = (lo + hi + 1) >> 1;
            if (lofs[mid] <= k) lo = mid; else hi = mid - 1;
        }
        bkt[hist[lo] + (k - lofs[lo])] = stage[k];
    }
}

// block per bucket -> per-node LDS hist/scan, LDS-staged scatter, linear flush
__global__ void k_build(const int* __restrict__ gbase, const int* __restrict__ bkt,
                        const float* __restrict__ x,
                        int* __restrict__ rs, int* __restrict__ ss,
                        float* __restrict__ dinv, float* __restrict__ sa,
                        int N, int E) {
    __shared__ int cnt[128], lrs[128], lcur[128];
    __shared__ int stg[BCAP];
    int b = blockIdx.x, t = threadIdx.x;
    int node_base = b << 7;
    int gb = gbase[b];
    int sz = gbase[b + 1] - gb;
    bool staged = (sz <= BCAP);
    if (t < 128) cnt[t] = 0;
    __syncthreads();
    const int* q = bkt + gb;
    for (int k = t; k < sz; k += BLK) atomicAdd(&cnt[(q[k] >> 17) & 127], 1);
    __syncthreads();
    if (t < 128) lrs[t] = cnt[t];
    __syncthreads();
    for (int o = 1; o < 128; o <<= 1) {
        int a = (t >= o && t < 128) ? lrs[t - o] : 0;
        __syncthreads();
        if (t < 128) lrs[t] += a;
        __syncthreads();
    }
    if (t < 128) {
        int ex = lrs[t] - cnt[t];
        lcur[t] = staged ? ex : gb + ex;
        int i = node_base + t;
        if (i < N) {
            rs[i] = gb + ex;
            float d = rsqrtf((float)cnt[t] + 1.0f);
            dinv[i] = d;
            sa[i] = x[i] * d;
        }
    }
    if (b == 0 && t == 0) rs[N] = E;
    __syncthreads();
    if (staged) {
        for (int k = t; k < sz; k += BLK) {
            int v = q[k];
            int pos = atomicAdd(&lcur[(v >> 17) & 127], 1);
            stg[pos] = v & 0x1FFFF;
        }
        __syncthreads();
        for (int k = t; k < sz; k += BLK) ss[gb + k] = stg[k];
    } else {
        for (int k = t; k < sz; k += BLK) {
            int v = q[k];
            int pos = atomicAdd(&lcur[(v >> 17) & 127], 1);
            ss[pos] = v & 0x1FFFF;
        }
    }
}

// ---- layers -------------------------------------------------------------

// layer 1 + fused layer-2 matvec: scalar gather -> F1 (lane=feature) ->
// Gh2[i,l] = dinv_i * sum_k F1_k * Wmid[k][l], via 32 shuffles
__global__ void k_l1aggG(const int* __restrict__ rs, const int* __restrict__ ss,
                         const float* __restrict__ sa, const float* __restrict__ dinv,
                         const float* __restrict__ Win, const float* __restrict__ bin,
                         const float* __restrict__ Wmid, _Float16* __restrict__ Gh, int N) {
    int t = blockIdx.x * blockDim.x + threadIdx.x;
    int i = t >> 5, l = t & 31;
    if (i >= N) return;
    float wcol[32];
    #pragma unroll
    for (int k = 0; k < 32; ++k) wcol[k] = Wmid[k * 32 + l];
    int beg = rs[i], end = rs[i + 1];
    float s = 0.f;
    for (int e = beg + l; e < end; e += 32) s += sa[ss[e]];
    #pragma unroll
    for (int m = 16; m; m >>= 1) s += __shfl_xor(s, m, 32);
    float d = dinv[i];
    float h = d * (s + sa[i]);
    float F = h * Win[l] + bin[l];
    F = F > 0.f ? F : 0.f;
    float g = 0.f;
    #pragma unroll
    for (int k = 0; k < 32; ++k) g += __shfl(F, k, 32) * wcol[k];
    Gh[t] = (_Float16)(g * d);
}

// Gh(fp16) = (Fh(fp16) @ W) * dinv, 8 nodes per 256-thread block
__global__ void k_matvec_scale(const _Float16* __restrict__ Fh, const float* __restrict__ W,
                               const float* __restrict__ dinv, _Float16* __restrict__ Gh, int N) {
    __shared__ float sW[1024];
    __shared__ float sH[256];
    int t = threadIdx.x;
    #pragma unroll
    for (int r = 0; r < 4; ++r) sW[r * 256 + t] = W[r * 256 + t];
    int base = blockIdx.x * 8;
    long long gidx = (long long)base * 32 + t;
    sH[t] = (gidx < (long long)N * 32) ? (float)Fh[gidx] : 0.f;
    __syncthreads();
    int il = t >> 5, j = t & 31;
    int i = base + il;
    if (i < N) {
        float acc = 0.f;
        #pragma unroll
        for (int k = 0; k < 32; ++k) acc += sH[il * 32 + k] * sW[k * 32 + j];
        Gh[(long long)i * 32 + j] = (_Float16)(acc * dinv[i]);
    }
}

// layer-2 aggregate: gather fp16 rows, combine+relu, write Fh (fp16)
__global__ void k_agg2(const int* __restrict__ rs, const int* __restrict__ ss,
                       const half8* __restrict__ G8, const float* __restrict__ dinv,
                       const float* __restrict__ b, half8* __restrict__ Fh8, int N) {
    int t = blockIdx.x * blockDim.x + threadIdx.x;
    int g = t >> 5;
    if (g >= N) return;
    int lane = t & 31, sub = lane >> 2, fl = lane & 3;
    int beg = rs[g], end = rs[g + 1];
    float acc[8];
    #pragma unroll
    for (int j = 0; j < 8; ++j) acc[j] = 0.f;
    if (sub == 0) {
        half8 v = G8[(long long)g * 4 + fl];
        #pragma unroll
        for (int j = 0; j < 8; ++j) acc[j] = (float)v[j];
    }
    int e = beg + sub;
    for (; e + 8 < end; e += 16) {
        int s0 = ss[e], s1 = ss[e + 8];
        half8 v0 = G8[(long long)s0 * 4 + fl];
        half8 v1 = G8[(long long)s1 * 4 + fl];
        #pragma unroll
        for (int j = 0; j < 8; ++j) acc[j] += (float)v0[j] + (float)v1[j];
    }
    for (; e < end; e += 8) {
        half8 v0 = G8[(long long)ss[e] * 4 + fl];
        #pragma unroll
        for (int j = 0; j < 8; ++j) acc[j] += (float)v0[j];
    }
    #pragma unroll
    for (int j = 0; j < 8; ++j) {
        acc[j] += __shfl_xor(acc[j], 4);
        acc[j] += __shfl_xor(acc[j], 8);
        acc[j] += __shfl_xor(acc[j], 16);
    }
    if (sub == 0) {
        float d = dinv[g];
        half8 o;
        #pragma unroll
        for (int j = 0; j < 8; ++j) {
            float v = d * acc[j] + b[fl * 8 + j];
            o[j] = (_Float16)(v > 0.f ? v : 0.f);
        }
        Fh8[(long long)g * 4 + fl] = o;
    }
}

// layer-3 aggregate + fused W_out dot: writes only sa[i] = (relu(...) . Wout)*dinv
__global__ void k_agg3(const int* __restrict__ rs, const int* __restrict__ ss,
                       const half8* __restrict__ G8, const float* __restrict__ dinv,
                       const float* __restrict__ b, const float* __restrict__ Wout,
                       float* __restrict__ sa, int N) {
    int t = blockIdx.x * blockDim.x + threadIdx.x;
    int g = t >> 5;
    if (g >= N) return;
    int lane = t & 31, sub = lane >> 2, fl = lane & 3;
    int beg = rs[g], end = rs[g + 1];
    float acc[8];
    #pragma unroll
    for (int j = 0; j < 8; ++j) acc[j] = 0.f;
    if (sub == 0) {
        half8 v = G8[(long long)g * 4 + fl];
        #pragma unroll
        for (int j = 0; j < 8; ++j) acc[j] = (float)v[j];
    }
    int e = beg + sub;
    for (; e + 8 < end; e += 16) {
        int s0 = ss[e], s1 = ss[e + 8];
        half8 v0 = G8[(long long)s0 * 4 + fl];
        half8 v1 = G8[(long long)s1 * 4 + fl];
        #pragma unroll
        for (int j = 0; j < 8; ++j) acc[j] += (float)v0[j] + (float)v1[j];
    }
    for (; e < end; e += 8) {
        half8 v0 = G8[(long long)ss[e] * 4 + fl];
        #pragma unroll
        for (int j = 0; j < 8; ++j) acc[j] += (float)v0[j];
    }
    #pragma unroll
    for (int j = 0; j < 8; ++j) {
        acc[j] += __shfl_xor(acc[j], 4);
        acc[j] += __shfl_xor(acc[j], 8);
        acc[j] += __shfl_xor(acc[j], 16);
    }
    if (sub == 0) {
        float d = dinv[g];
        float p = 0.f;
        #pragma unroll
        for (int j = 0; j < 8; ++j) {
            float v = d * acc[j] + b[fl * 8 + j];
            v = v > 0.f ? v : 0.f;
            p += v * Wout[fl * 8 + j];
        }
        p += __shfl_xor(p, 1, 32);
        p += __shfl_xor(p, 2, 32);
        if (fl == 0) sa[g] = p * d;
    }
}

// layer 4: scalar gather-reduce + sigmoid, fused
__global__ void k_final_agg(const int* __restrict__ rs, const int* __restrict__ ss,
                            const float* __restrict__ sa, const float* __restrict__ dinv,
                            const float* __restrict__ bout, float* __restrict__ out, int N) {
    int t = blockIdx.x * blockDim.x + threadIdx.x;
    int i = t >> 5, l = t & 31;
    if (i >= N) return;
    int beg = rs[i], end = rs[i + 1];
    float s = 0.f;
    for (int e = beg + l; e < end; e += 32) s += sa[ss[e]];
    #pragma unroll
    for (int m = 16; m; m >>= 1) s += __shfl_xor(s, m, 32);
    if (l == 0) {
        float z = dinv[i] * (s + sa[i]) + bout[0];
        out[i] = 1.0f / (1.0f + expf(-z));
    }
}

extern "C" void kernel_launch(void* const* d_in, const int* in_sizes, int n_in,
                              void* d_out, int out_size, void* d_ws, size_t ws_size,
                              hipStream_t stream) {
    const float* x    = (const float*)d_in[0];
    const int*   ei   = (const int*)  d_in[1];
    const float* Win  = (const float*)d_in[2];
    const float* bin  = (const float*)d_in[3];
    const float* Wmid = (const float*)d_in[4];
    const float* bmid = (const float*)d_in[5];
    const float* Wout = (const float*)d_in[6];
    const float* bout = (const float*)d_in[7];
    float* out = (float*)d_out;

    int N = in_sizes[0];
    int E = in_sizes[1] / 2;
    const int* src = ei;
    const int* dst = ei + E;

    int NB = (N + 127) >> 7;                       // 782 buckets of 128 nodes
    int chunk = (E + NBLK - 1) / NBLK;             // 12500

    // workspace layout (bkt aliases Gh+Fh: k_build finishes before Gh written)
    int* tot    = (int*)d_ws;                      // 1024
    int* cursor = tot + 1024;                      // 1024
    int* gbase  = cursor + 1024;                   // 1024 (783 used)
    int* rs     = gbase + 1024;                    // N+4
    int* ss     = rs + N + 4;                      // E
    float* dinv = (float*)(ss + E);                // N
    float* sa   = dinv + N;                        // N
    _Float16* Gh = (_Float16*)(sa + N);            // 32N fp16
    _Float16* Fh = Gh + 32 * (size_t)N;            // 32N fp16
    int* bkt    = (int*)Gh;                        // E ints (= Gh+Fh bytes)

    int NT   = N * 32;
    int gN32 = (NT + BLK - 1) / BLK;
    int gMV  = (N + 7) / 8;

    // CSR build: hist -> scan -> LDS multisplit place -> per-bucket node sort
    hipMemsetAsync(tot, 0, 1024 * 4, stream);
    k_hist<<<NBLK, BLK, 0, stream>>>(dst, tot, E, chunk);
    k_scan782<<<1, BLK, 0, stream>>>(tot, cursor, gbase);
    k_place<<<NBLK, PBLK, 0, stream>>>(src, dst, cursor, bkt, E, chunk);
    k_build<<<NB, BLK, 0, stream>>>(gbase, bkt, x, rs, ss, dinv, sa, N, E);

    // layer 1 (+ fused layer-2 matvec) -> Gh
    k_l1aggG<<<gN32, BLK, 0, stream>>>(rs, ss, sa, dinv, Win, bin, Wmid, Gh, N);

    // layer 2 aggregate -> Fh (fp16)
    k_agg2<<<gN32, BLK, 0, stream>>>(rs, ss, (const half8*)Gh, dinv, bmid, (half8*)Fh, N);

    // layer-3 matvec: Fh -> Gh
    k_matvec_scale<<<gMV, BLK, 0, stream>>>(Fh, Wmid, dinv, Gh, N);

    // layer 3 aggregate (+ fused W_out dot) -> sa
    k_agg3<<<gN32, BLK, 0, stream>>>(rs, ss, (const half8*)Gh, dinv, bmid, Wout, sa, N);

    // layer 4: scalar aggregate + sigmoid
    k_final_agg<<<gN32, BLK, 0, stream>>>(rs, ss, sa, dinv, bout, out, N);
}